// Round 8
// baseline (156.109 us; speedup 1.0000x reference)
//
#include <hip/hip_runtime.h>
#include <hip/hip_bf16.h>
#include <math.h>

typedef float f32x4 __attribute__((ext_vector_type(4)));
typedef short s16x8 __attribute__((ext_vector_type(8)));

#define NS 2048
#define NH 16
#define ND 64
#define QTILE 256
#define KVB 64
#define NT (NS / KVB)
#define QSCALE 0.18033688f   // 0.125 * log2(e)
#define DEFER_THR 11.5f      // T13 defer-max threshold (log2 units)

__device__ __forceinline__ unsigned cvtpk(float lo, float hi) {
    unsigned r;
    asm("v_cvt_pk_bf16_f32 %0, %1, %2" : "=v"(r) : "v"(lo), "v"(hi));
    return r;
}

// v5: 32 q-rows per wave (two 16-row m-tiles) -> wave count halves -> per-CU
// LDS read traffic (the measured bottleneck: ~75% LDS-pipe busy + 15% conflict)
// halves. K-frags feed 4 MFMAs each, V-frags 2; P has 2 per-wave slots so PV
// reads V once. All fragment mappings unchanged from verified v4.
__global__ __launch_bounds__(512, 2)
void usp_attn(const float* __restrict__ Qg, const float* __restrict__ Kg,
              const float* __restrict__ Vg, float* __restrict__ Og) {
    __shared__ unsigned short Klds[2][64 * 64];   // [buf][kv][d]  swz: d ^ ((kv&7)<<3)
    __shared__ unsigned short Vt[2][64 * 64];     // [buf][d][kv]  swz: kv ^ (((d>>1)&7)<<3)
    __shared__ unsigned short Plds[8][2 * 16 * 64]; // [wave][mt][q][kv] swz: kv ^ ((q&7)<<3)

    const int tid  = threadIdx.x;
    const int w    = tid >> 6;     // wave 0..7
    const int lane = tid & 63;
    const int g    = lane >> 4;    // 0..3
    const int x    = lane & 15;

    // XCD-chunked swizzle (256 blocks, 8 XCDs, chunk=32, bijective)
    int bid = blockIdx.x;
    int wg  = (bid & 7) * 32 + (bid >> 3);
    int qt  = wg & 7;             // 8 q-tiles per head
    int bh  = wg >> 3;            // 0..31
    int b   = bh >> 4;
    int h   = bh & 15;
    int q0  = qt * QTILE;

    const int srow = NH * ND;
    const size_t base = ((size_t)b * NS * NH + h) * ND;

    // ---- Q fragments (B-operand) for both m-tiles ----
    s16x8 qf[2][2];
#pragma unroll
    for (int mt = 0; mt < 2; ++mt) {
        const float* qp = Qg + base + (size_t)(q0 + w * 32 + mt * 16 + x) * srow;
#pragma unroll
        for (int ks = 0; ks < 2; ++ks) {
            int d0 = ks * 32 + g * 8;
            f32x4 a = *(const f32x4*)(qp + d0);
            f32x4 c = *(const f32x4*)(qp + d0 + 4);
            union { s16x8 v; unsigned u[4]; } r;
            r.u[0] = cvtpk(a[0] * QSCALE, a[1] * QSCALE);
            r.u[1] = cvtpk(a[2] * QSCALE, a[3] * QSCALE);
            r.u[2] = cvtpk(c[0] * QSCALE, c[1] * QSCALE);
            r.u[3] = cvtpk(c[2] * QSCALE, c[3] * QSCALE);
            qf[mt][ks] = r.v;
        }
    }

    f32x4 oacc[2][4];   // [mt][dt]: O[qrow_mt][d = 16*dt + 4g + reg]
    float mrun[2] = {-INFINITY, -INFINITY}, lrun[2] = {0.f, 0.f};
#pragma unroll
    for (int mt = 0; mt < 2; ++mt)
#pragma unroll
        for (int dt = 0; dt < 4; ++dt) oacc[mt][dt] = f32x4{0.f, 0.f, 0.f, 0.f};

    // ---- staging: 512 threads cover 64 kv x 64 d in 2 passes ----
    const int sub = tid >> 4;          // kv 0..31
    const int c4  = (tid & 15) * 4;    // d column
    const float* kb = Kg + base + (size_t)sub * srow + c4;
    const float* vb = Vg + base + (size_t)sub * srow + c4;

    f32x4 kreg[2], vreg[2];
#define LOADT(t) do { \
        size_t off = (size_t)(t) * KVB * srow; \
        kreg[0] = *(const f32x4*)(kb + off); \
        kreg[1] = *(const f32x4*)(kb + off + (size_t)32 * srow); \
        vreg[0] = *(const f32x4*)(vb + off); \
        vreg[1] = *(const f32x4*)(vb + off + (size_t)32 * srow); \
    } while (0)

#define STORET(bf) do { \
        _Pragma("unroll") \
        for (int p = 0; p < 2; ++p) { \
            int kv = sub + 32 * p; \
            int de = c4 ^ ((kv & 7) << 3); \
            *(uint2*)(&Klds[bf][kv * 64 + de]) = \
                uint2{cvtpk(kreg[p][0], kreg[p][1]), cvtpk(kreg[p][2], kreg[p][3])}; \
            unsigned va = cvtpk(vreg[p][0], vreg[p][1]); \
            unsigned vb2 = cvtpk(vreg[p][2], vreg[p][3]); \
            int s01 = kv ^ (((c4 >> 1) & 7) << 3); \
            int s23 = kv ^ ((((c4 >> 1) + 1) & 7) << 3); \
            Vt[bf][(c4 + 0) * 64 + s01] = (unsigned short)va; \
            Vt[bf][(c4 + 1) * 64 + s01] = (unsigned short)(va >> 16); \
            Vt[bf][(c4 + 2) * 64 + s23] = (unsigned short)vb2; \
            Vt[bf][(c4 + 3) * 64 + s23] = (unsigned short)(vb2 >> 16); \
        } \
    } while (0)

    LOADT(0);
    STORET(0);
    LOADT(1);
    __syncthreads();

    unsigned short* Pw = &Plds[w][0];
    const int rsw = (x & 7) << 3;      // swizzle for K rows (kv&7=x&7) and P rows (q&7=x&7)
    const int vsw = (x >> 1) << 3;     // Vt swizzle for d = 16dt + x

    for (int t = 0; t < NT; ++t) {
        const unsigned short* Kc = &Klds[t & 1][0];
        const unsigned short* Vc = &Vt[t & 1][0];

        if (t + 1 < NT) STORET((t + 1) & 1);
        if (t + 2 < NT) LOADT(t + 2);

        // ---- S' = K·Q^T for both m-tiles; K-frags read once, used 2x ----
        f32x4 sc[2][4];
#pragma unroll
        for (int mt = 0; mt < 2; ++mt)
#pragma unroll
            for (int nt = 0; nt < 4; ++nt) sc[mt][nt] = f32x4{0.f, 0.f, 0.f, 0.f};
        __builtin_amdgcn_s_setprio(1);
#pragma unroll
        for (int nt = 0; nt < 4; ++nt) {
            int krow = (16 * nt + x) * 64;
            s16x8 kf0 = *(const s16x8*)(&Kc[krow + ((8 * g) ^ rsw)]);
            s16x8 kf1 = *(const s16x8*)(&Kc[krow + ((32 + 8 * g) ^ rsw)]);
            sc[0][nt] = __builtin_amdgcn_mfma_f32_16x16x32_bf16(kf0, qf[0][0], sc[0][nt], 0, 0, 0);
            sc[0][nt] = __builtin_amdgcn_mfma_f32_16x16x32_bf16(kf1, qf[0][1], sc[0][nt], 0, 0, 0);
            sc[1][nt] = __builtin_amdgcn_mfma_f32_16x16x32_bf16(kf0, qf[1][0], sc[1][nt], 0, 0, 0);
            sc[1][nt] = __builtin_amdgcn_mfma_f32_16x16x32_bf16(kf1, qf[1][1], sc[1][nt], 0, 0, 0);
        }
        __builtin_amdgcn_s_setprio(0);

        // ---- online softmax per m-tile (lane-local rows, T13 defer-max) ----
#pragma unroll
        for (int mt = 0; mt < 2; ++mt) {
            float mx = sc[mt][0][0];
#pragma unroll
            for (int nt = 0; nt < 4; ++nt)
#pragma unroll
                for (int r = 0; r < 4; ++r) mx = fmaxf(mx, sc[mt][nt][r]);
            mx = fmaxf(mx, __shfl_xor(mx, 16));
            mx = fmaxf(mx, __shfl_xor(mx, 32));
            if (!__all(mx - mrun[mt] <= DEFER_THR)) {
                float mnew = fmaxf(mrun[mt], mx);
                float alpha = exp2f(mrun[mt] - mnew);
                mrun[mt] = mnew;
                lrun[mt] *= alpha;
#pragma unroll
                for (int dt = 0; dt < 4; ++dt)
#pragma unroll
                    for (int r = 0; r < 4; ++r) oacc[mt][dt][r] *= alpha;
            }
            float rs = 0.f;
#pragma unroll
            for (int nt = 0; nt < 4; ++nt) {
                float p0 = exp2f(sc[mt][nt][0] - mrun[mt]);
                float p1 = exp2f(sc[mt][nt][1] - mrun[mt]);
                float p2 = exp2f(sc[mt][nt][2] - mrun[mt]);
                float p3 = exp2f(sc[mt][nt][3] - mrun[mt]);
                rs += (p0 + p1) + (p2 + p3);
                *(uint2*)(&Pw[mt * 1024 + x * 64 + ((16 * nt + 4 * g) ^ rsw)]) =
                    uint2{cvtpk(p0, p1), cvtpk(p2, p3)};
            }
            rs += __shfl_xor(rs, 16);
            rs += __shfl_xor(rs, 32);
            lrun[mt] += rs;
        }

        // ---- O^T += V^T·P^T; V-frags read once, used for both m-tiles ----
        __builtin_amdgcn_s_setprio(1);
#pragma unroll
        for (int ks = 0; ks < 2; ++ks) {
            int k0 = 32 * ks + 8 * g;
            s16x8 pf0 = *(const s16x8*)(&Pw[x * 64 + (k0 ^ rsw)]);
            s16x8 pf1 = *(const s16x8*)(&Pw[1024 + x * 64 + (k0 ^ rsw)]);
#pragma unroll
            for (int dt = 0; dt < 4; ++dt) {
                s16x8 vf = *(const s16x8*)(&Vc[(16 * dt + x) * 64 + (k0 ^ vsw)]);
                oacc[0][dt] = __builtin_amdgcn_mfma_f32_16x16x32_bf16(vf, pf0, oacc[0][dt], 0, 0, 0);
                oacc[1][dt] = __builtin_amdgcn_mfma_f32_16x16x32_bf16(vf, pf1, oacc[1][dt], 0, 0, 0);
            }
        }
        __builtin_amdgcn_s_setprio(0);

        __syncthreads();
    }

    // ---- epilogue ----
#pragma unroll
    for (int mt = 0; mt < 2; ++mt) {
        float inv = 1.0f / lrun[mt];
        float* op = Og + base + (size_t)(q0 + w * 32 + mt * 16 + x) * srow;
#pragma unroll
        for (int dt = 0; dt < 4; ++dt) {
            f32x4 r = oacc[mt][dt];
            r[0] *= inv; r[1] *= inv; r[2] *= inv; r[3] *= inv;
            *(f32x4*)(op + 16 * dt + 4 * g) = r;
        }
    }
}

extern "C" void kernel_launch(void* const* d_in, const int* in_sizes, int n_in,
                              void* d_out, int out_size, void* d_ws, size_t ws_size,
                              hipStream_t stream) {
    const float* Q = (const float*)d_in[0];
    const float* K = (const float*)d_in[1];
    const float* V = (const float*)d_in[2];
    float* O = (float*)d_out;
    usp_attn<<<dim3(256), dim3(512), 0, stream>>>(Q, K, V, O);
}